// Round 5
// baseline (345.535 us; speedup 1.0000x reference)
//
#include <hip/hip_runtime.h>
#include <math.h>

#define DI static __device__ __forceinline__

DI float eluf(float x){ return x > 0.f ? x : expm1f(x); }
DI float lreluf(float x){ return x > 0.f ? x : 0.2f*x; }
DI float sigmf(float x){ return 1.f/(1.f+expf(-x)); }

typedef unsigned short u16;
typedef unsigned int   u32;
typedef __attribute__((ext_vector_type(8))) short short8_t;
typedef __attribute__((ext_vector_type(4))) float f32x4;

DI u16 bf16rne(float f){
  u32 u = __float_as_uint(f);
  u += 0x7fffu + ((u>>16)&1u);
  return (u16)(u>>16);
}

DI f32x4 bmfma(short8_t a, short8_t b, f32x4 c){
  return __builtin_amdgcn_mfma_f32_16x16x32_bf16(a, b, c, 0, 0, 0);
}

constexpr int N=200, E=3200, HID=64, NH=16, OUTD=128, CAT=2048, SEQD=2240;

// ---- per-graph f32 scratch offsets (in floats) ----
constexpr int OH0   = 0;
constexpr int OWH   = OH0 + N*HID;
constexpr int OASN  = OWH + NH*N*OUTD;
constexpr int OADN  = OASN + NH*N;
constexpr int OH1   = OADN + NH*N;
constexpr int OXW1  = OH1 + N*CAT;
constexpr int OXW2  = OXW1 + 256;
constexpr int OEW1  = OXW2 + 256;
constexpr int OS1   = OEW1 + E;
constexpr int ODEG1 = OS1 + E;
constexpr int OSS1  = ODEG1 + 256;   // = ODEG1+256 (inline ns relies on this)
constexpr int ORAW1 = OSS1 + 256;
constexpr int OWH2  = ORAW1 + 256;
constexpr int OAS2  = OWH2 + N*OUTD;
constexpr int OAD2  = OAS2 + 256;
constexpr int OEWV  = OAD2 + 256;
constexpr int OH2B  = OEWV + E;
constexpr int OXS2  = OH2B + N*OUTD;
constexpr int OXD2  = OXS2 + 256;
constexpr int ODEG2 = OXD2 + 256;
constexpr int OSS2  = ODEG2 + 256;   // = ODEG2+256
constexpr int ORAW2 = OSS2 + 256;
constexpr int ORAW3 = ORAW2 + 256;
constexpr int PGF   = ORAW3 + 256;
constexpr int GLOBF = 10624;
constexpr int TOTF  = GLOBF + 2*PGF;

// ---- static device scratch ----
__device__ __attribute__((aligned(16))) float G_F[TOTF];
__device__ float G_E2PART[(size_t)4*2*E*OUTD];    // ew2full partials [hg=4][g][e][128]
__device__ float G_EDOTH[2*NH*E];
__device__ float G_WHHT[2*2*128*512];
__device__ int   G_PIDX[2*N*N];
__device__ __attribute__((aligned(16))) u16 G_WGAT_T[NH*OUTD*HID];  // [h][o][c] bf16
__device__ __attribute__((aligned(16))) u16 G_WOUT_T[OUTD*CAT];     // [n][q] bf16
__device__ __attribute__((aligned(16))) u16 G_EATTR_BF[2*E*HID];    // [g][e][c] bf16

DI float* gf(int g){ return G_F + GLOBF + (size_t)g*PGF; }
DI float* gwe_ae(){ return G_F; }
DI float* gv_e(){ return G_F + 1024; }
DI float* gy0(){ return G_F + 3072; }
DI float* gy1(){ return G_F + 3584; }
DI float* gxseq(){ return G_F + 4096; }
DI float* gxg(){ return G_F + 8576; }
DI int*   gpidx(int g){ return G_PIDX + g*N*N; }

struct GraphIn {
  const float *feat, *eattr, *adj, *n2n;
  const int   *eidx;
};

struct Params {
  GraphIn g[2];
  const float *W_h, *W_gat, *a_src, *a_dst, *a_e, *We_gat;
  const float *W_out, *ao_src, *ao_dst, *ao_e, *We_out;
  const float *ep1_w, *ep1_b, *ep2_w, *ep2_b;
  const float *g1_w, *g1_b, *g2_w, *g2_b, *g3_w, *g3_b;
  const float *Wih0, *Whh0, *b0, *Wih1, *Whh1, *b1, *fc_w, *fc_b;
  float *out;
};

// ---- fused init: zero atomics (incl xw1 targets), pidx, Whh^T, precontract, h0+g1dot, bf16 ----
constexpr int ZPG  = 2*E + 1024 + 768;        // per-graph floats to zero
constexpr int IB_Z = (2*ZPG+255)/256;
constexpr int IB_C = (2*N*N+255)/256;
constexpr int IB_D = (2*2*512*128)/256;
constexpr int IB_E = (NH*HID+CAT+3)/4;
constexpr int IB_H = (2*N+3)/4;
constexpr int IB_W1 = (NH*OUTD*HID)/256;      // 512
constexpr int IB_W2 = (OUTD*CAT)/256;         // 1024
constexpr int IB_EA = (2*E*HID)/256;          // 1600
__global__ void k_init(Params P){
  int b = blockIdx.x, tid = threadIdx.x;
  if (b < IB_Z){
    int i = b*256 + tid;
    if (i < 2*ZPG){
      int g = i/ZPG, r = i%ZPG;
      int addr;
      if (r < E) addr = OEW1+r;
      else if (r < 2*E) addr = OEWV+(r-E);
      else if (r < 2*E+512) addr = ODEG1+(r-2*E);
      else if (r < 2*E+1024) addr = ODEG2+(r-2*E-512);
      else if (r < 2*E+1280) addr = OXW1+(r-2*E-1024);
      else if (r < 2*E+1536) addr = OXW2+(r-2*E-1280);
      else addr = ORAW2+(r-2*E-1536);
      gf(g)[addr] = 0.f;
    }
  } else if (b < IB_Z+IB_C){
    int i = (b-IB_Z)*256 + tid; if (i < 2*N*N) G_PIDX[i] = -1;
  } else if (b < IB_Z+IB_C+IB_D){
    int idx = (b-IB_Z-IB_C)*256 + tid;
    int l = idx >> 17;
    int r = idx & 131071;
    int d = r >> 16;
    int r2 = r & 65535;
    int gate = r2 & 511;
    int k = r2 >> 9;
    const float* Whh = l ? P.Whh1 : P.Whh0;
    G_WHHT[idx] = Whh[((size_t)d*512+gate)*128 + k];
  } else if (b < IB_Z+IB_C+IB_D+IB_E){
    int gid = (b-IB_Z-IB_C-IB_D)*4 + (tid>>6);
    int lane = tid & 63;
    if (gid < NH*HID){
      int h = gid/HID, c = gid%HID;
      const float* W = P.We_gat + (size_t)(h*HID+c)*OUTD;
      const float* a = P.a_e + h*OUTD;
      float acc = 0.f;
      for (int o=lane;o<OUTD;o+=64) acc += W[o]*a[o];
      for (int off=32;off>0;off>>=1) acc += __shfl_down(acc,off);
      if (lane==0) gwe_ae()[gid] = acc;
    } else if (gid < NH*HID+CAT){
      int c = gid - NH*HID;
      const float* W = P.We_out + (size_t)c*OUTD;
      float acc = 0.f;
      for (int o=lane;o<OUTD;o+=64) acc += W[o]*P.ao_e[o];
      for (int off=32;off>0;off>>=1) acc += __shfl_down(acc,off);
      if (lane==0) gv_e()[c] = acc;
    }
  } else if (b < IB_Z+IB_C+IB_D+IB_E+IB_H){
    int unit = (b-IB_Z-IB_C-IB_D-IB_E)*4 + (tid>>6);
    if (unit >= 2*N) return;
    int g = unit / N, n = unit % N, c = tid & 63;
    const float* feat = P.g[g].feat;
    float acc = 0.f;
    for (int k=0;k<HID;k++) acc += feat[n*HID+k]*P.W_h[k*HID+c];
    float v = eluf(acc);
    float* f = gf(g);
    f[OH0 + n*HID + c] = v;
    float r = v*P.g1_w[c];
    for (int off=32;off>0;off>>=1) r += __shfl_down(r,off);
    if (c==0) f[ORAW1+n] = r;
  } else if (b < IB_Z+IB_C+IB_D+IB_E+IB_H+IB_W1){
    int i = (b-(IB_Z+IB_C+IB_D+IB_E+IB_H))*256 + tid;
    int h = i>>13, o = (i>>6)&127, c = i&63;
    G_WGAT_T[i] = bf16rne(P.We_gat[(size_t)(h*HID+c)*OUTD + o]);
  } else if (b < IB_Z+IB_C+IB_D+IB_E+IB_H+IB_W1+IB_W2){
    int i = (b-(IB_Z+IB_C+IB_D+IB_E+IB_H+IB_W1))*256 + tid;
    int n = i>>11, q = i&2047;
    G_WOUT_T[i] = bf16rne(P.We_out[(size_t)q*OUTD + n]);
  } else {
    int i = (b-(IB_Z+IB_C+IB_D+IB_E+IB_H+IB_W1+IB_W2))*256 + tid;
    int g = i >= E*HID ? 1 : 0;
    G_EATTR_BF[i] = bf16rne(P.g[g].eattr[i - g*E*HID]);
  }
}
constexpr int IB_TOT = IB_Z+IB_C+IB_D+IB_E+IB_H+IB_W1+IB_W2+IB_EA;

// ================= mega kernel bodies (independent stages, one launch) =========

// ---- e2p: 32 edges x 4 heads per block, K=512 mm2, rolling 2-deep Wo pipe ----
DI void e2p_body(Params& P, int idx, char* smem){
  int g = idx/400, r2 = idx%400, hg = r2/100, eb = r2%100;
  int tid = threadIdx.x;
  int wave = tid>>6, lane = tid&63, l16 = lane&15, l4 = lane>>4;
  u16* Tlds = (u16*)smem;                       // 32KB, row-XOR swizzled
  int e0 = eb*32;
  int nt0 = wave*2;
  const u16* ea = G_EATTR_BF + ((size_t)g*E + e0)*HID;
  short8_t af00 = *(const short8_t*)(ea + l16*HID + l4*8);
  short8_t af01 = *(const short8_t*)(ea + l16*HID + 32 + l4*8);
  short8_t af10 = *(const short8_t*)(ea + (16+l16)*HID + l4*8);
  short8_t af11 = *(const short8_t*)(ea + (16+l16)*HID + 32 + l4*8);
  float ew1p0[4] = {0.f,0.f,0.f,0.f}, ewvp0[4] = {0.f,0.f,0.f,0.f};
  float ew1p1[4] = {0.f,0.f,0.f,0.f}, ewvp1[4] = {0.f,0.f,0.f,0.f};
  for (int hh=0; hh<4; hh++){
    int h = hg*4 + hh;
    const u16* Wg = G_WGAT_T + (size_t)h*OUTD*HID;
    #pragma unroll
    for (int nn=0; nn<2; nn++){
      int nt = nt0 + nn;
      const u16* Wgn = Wg + (size_t)(nt*16 + l16)*HID + l4*8;
      short8_t wg0 = *(const short8_t*)Wgn;
      short8_t wg1 = *(const short8_t*)(Wgn + 32);
      f32x4 d0 = {0.f,0.f,0.f,0.f}, d1 = {0.f,0.f,0.f,0.f};
      d0 = bmfma(af00, wg0, d0);
      d1 = bmfma(af10, wg0, d1);
      d0 = bmfma(af01, wg1, d0);
      d1 = bmfma(af11, wg1, d1);
      int qg = h*OUTD + nt*16 + l16;
      float w1 = P.ep1_w[2*CAT + qg];
      float wv = gv_e()[qg];
      int qloc = hh*128 + nt*16 + l16;
      #pragma unroll
      for (int r=0;r<4;r++){
        float v0 = d0[r] > 0.f ? d0[r] : expm1f(d0[r]);
        float v1 = d1[r] > 0.f ? d1[r] : expm1f(d1[r]);
        ew1p0[r] += v0*w1; ewvp0[r] += v0*wv;
        ew1p1[r] += v1*w1; ewvp1[r] += v1*wv;
        int row = l4*4 + r;
        int byt = (row*1024 + qloc*2) ^ ((row&7)<<4);
        *(u16*)((char*)Tlds + byt) = bf16rne(v0);
        *(u16*)((char*)Tlds + byt + 16384) = bf16rne(v1);   // rows 16..31
      }
    }
  }
  const u16* WoA = G_WOUT_T + (size_t)(wave*32 + l16)*CAT + hg*512 + l4*8;
  const u16* WoB = WoA + 16*CAT;
  short8_t w0a = *(const short8_t*)WoA;
  short8_t w0b = *(const short8_t*)WoB;
  short8_t w1a = *(const short8_t*)(WoA + 32);
  short8_t w1b = *(const short8_t*)(WoB + 32);
  float* f = gf(g);
  #pragma unroll
  for (int r=0;r<4;r++){
    float a0 = ew1p0[r], b0 = ewvp0[r], a1 = ew1p1[r], b1 = ewvp1[r];
    a0 += __shfl_xor(a0,1); b0 += __shfl_xor(b0,1); a1 += __shfl_xor(a1,1); b1 += __shfl_xor(b1,1);
    a0 += __shfl_xor(a0,2); b0 += __shfl_xor(b0,2); a1 += __shfl_xor(a1,2); b1 += __shfl_xor(b1,2);
    a0 += __shfl_xor(a0,4); b0 += __shfl_xor(b0,4); a1 += __shfl_xor(a1,4); b1 += __shfl_xor(b1,4);
    a0 += __shfl_xor(a0,8); b0 += __shfl_xor(b0,8); a1 += __shfl_xor(a1,8); b1 += __shfl_xor(b1,8);
    if (l16==0){
      int e = e0 + l4*4 + r;
      atomicAdd(&f[OEW1+e], a0);
      atomicAdd(&f[OEWV+e], b0);
      atomicAdd(&f[OEW1+e+16], a1);
      atomicAdd(&f[OEWV+e+16], b1);
    }
  }
  __syncthreads();
  f32x4 acc00 = {0.f,0.f,0.f,0.f}, acc01 = {0.f,0.f,0.f,0.f};
  f32x4 acc10 = {0.f,0.f,0.f,0.f}, acc11 = {0.f,0.f,0.f,0.f};
  #pragma unroll
  for (int ks=0; ks<16; ks++){
    short8_t na = w0a, nb = w0b;
    if (ks < 14){
      na = *(const short8_t*)(WoA + (ks+2)*32);
      nb = *(const short8_t*)(WoB + (ks+2)*32);
    }
    int byt = (l16*1024 + ks*64 + l4*16) ^ ((l16&7)<<4);
    short8_t a0 = *(const short8_t*)((const char*)Tlds + byt);
    short8_t a1 = *(const short8_t*)((const char*)Tlds + byt + 16384);
    acc00 = bmfma(a0, w0a, acc00);
    acc10 = bmfma(a1, w0a, acc10);
    acc01 = bmfma(a0, w0b, acc01);
    acc11 = bmfma(a1, w0b, acc11);
    w0a = w1a; w0b = w1b; w1a = na; w1b = nb;
  }
  float* dst = G_E2PART + (((size_t)hg*2 + g)*E + e0)*OUTD;
  #pragma unroll
  for (int r=0;r<4;r++){
    int ee = l4*4 + r;
    dst[(size_t)ee*OUTD + wave*32 + l16]      = acc00[r];
    dst[(size_t)ee*OUTD + wave*32 + 16 + l16] = acc01[r];
    dst[(size_t)(16+ee)*OUTD + wave*32 + l16]      = acc10[r];
    dst[(size_t)(16+ee)*OUTD + wave*32 + 16 + l16] = acc11[r];
  }
}

// ---- EDOTH fp32: 16 edges x 16 heads per block, LDS-staged (+1 pad) ----
DI void edoth_body(Params& P, int idx, float* s){
  int tid = threadIdx.x;
  int g = idx / (E/16);
  int e0 = (idx % (E/16)) * 16;
  float (*ea)[HID+1] = (float(*)[HID+1])s;
  float (*wa)[HID+1] = (float(*)[HID+1])(s + 16*(HID+1));
  {
    int row = tid >> 4, c0 = (tid & 15)*4;
    float4 v = *(const float4*)&P.g[g].eattr[(size_t)(e0+row)*HID + c0];
    ea[row][c0]=v.x; ea[row][c0+1]=v.y; ea[row][c0+2]=v.z; ea[row][c0+3]=v.w;
    float4 w = *(const float4*)&gwe_ae()[row*HID + c0];
    wa[row][c0]=w.x; wa[row][c0+1]=w.y; wa[row][c0+2]=w.z; wa[row][c0+3]=w.w;
  }
  __syncthreads();
  int h = tid >> 4, el = tid & 15;
  float acc = 0.f;
  #pragma unroll
  for (int c=0;c<HID;c++) acc += ea[el][c]*wa[h][c];
  G_EDOTH[((size_t)g*NH + h)*E + e0 + el] = acc;
}

// ---- Wh: one (n,h) per block (tid<128 active); h==NH slice does gpool1 ----
DI void wh_body(Params& P, int idx, float* s){
  int o = threadIdx.x;
  if (o >= 128) return;     // full waves 2-3 exit before any barrier
  int g = idx / (N*(NH+1));
  int r = idx % (N*(NH+1));
  int h = r / N, n = r % N;
  float* f = gf(g);
  if (h == NH){
    if (n != 0) return;
    float* att = s;          // [N]
    float* sb  = s + 200;    // [128]
    for (int j = o; j < N; j += 128) att[j] = sigmf(f[ORAW1+j] + P.g1_b[0]);
    __syncthreads();
    float m = -3e38f;
    for (int j = o; j < N; j += 128) m = fmaxf(m, att[j]);
    sb[o] = m; __syncthreads();
    for (int sft=64;sft>0;sft>>=1){ if (o<sft) sb[o]=fmaxf(sb[o],sb[o+sft]); __syncthreads(); }
    m = sb[0]; __syncthreads();
    float ss = 0.f;
    for (int j = o; j < N; j += 128){ float e = expf(att[j]-m); ss += e; }
    sb[o] = ss; __syncthreads();
    for (int sft=64;sft>0;sft>>=1){ if (o<sft) sb[o]+=sb[o+sft]; __syncthreads(); }
    float inv = 1.f/sb[0]; __syncthreads();
    for (int j = o; j < N; j += 128) att[j] = expf(att[j]-m)*inv;
    __syncthreads();
    if (o < HID){
      float acc = 0.f;
      for (int j=0;j<N;j++) acc += att[j]*f[OH0 + j*HID + o];
      gxseq()[g*SEQD + o] = acc;
    }
    return;
  }
  float* hs   = s;          // [64]
  float* sred = s + 64;     // [128]
  float* dred = s + 192;    // [128]
  if (o < HID) hs[o] = f[OH0 + n*HID + o];
  __syncthreads();
  const float* W = P.W_gat + (size_t)h*HID*OUTD + o;
  float acc = 0.f;
  for (int c=0;c<HID;c++) acc += hs[c]*W[(size_t)c*OUTD];
  f[OWH + ((size_t)h*N + n)*OUTD + o] = acc;
  sred[o] = acc*P.a_src[h*OUTD+o];
  dred[o] = acc*P.a_dst[h*OUTD+o];
  __syncthreads();
  for (int sft=64;sft>0;sft>>=1){ if (o<sft){ sred[o]+=sred[o+sft]; dred[o]+=dred[o+sft]; } __syncthreads(); }
  if (o==0){ f[OASN+h*N+n]=sred[0]; f[OADN+h*N+n]=dred[0]; }
}

// ---- pairIdx: last edge wins ----
DI void pairs_body(Params& P, int idx){
  int g = idx / 13;
  int e = (idx % 13)*256 + threadIdx.x;
  if (e >= E) return;
  const int* ei = P.g[g].eidx;
  atomicMax(&gpidx(g)[ei[e]*N + ei[E+e]], e);
}

constexpr int MB_E2P = 800, MB_ED = 400, MB_WH = 2*N*(NH+1), MB_PR = 26;
__global__ __launch_bounds__(256) void k_mega(Params P){
  __shared__ __attribute__((aligned(16))) char smem[32768];
  int b = blockIdx.x;
  if (b < MB_E2P) e2p_body(P, b, smem);
  else if (b < MB_E2P+MB_ED) edoth_body(P, b-MB_E2P, (float*)smem);
  else if (b < MB_E2P+MB_ED+MB_WH) wh_body(P, b-(MB_E2P+MB_ED), (float*)smem);
  else pairs_body(P, b-(MB_E2P+MB_ED+MB_WH));
}

// ---- GAT layer 1: 4 nodes/block + fused xw1/g2raw partial dots ----
__global__ void k_att1(Params P){
  int nb = blockIdx.x, h = blockIdx.y, g = blockIdx.z, tid = threadIdx.x;
  int n0 = nb*4;
  __shared__ float z[4][N];
  __shared__ float red[128];
  __shared__ float sinv[4];
  __shared__ float lxr[2][12];
  float* f = gf(g);
  const float* adj = P.g[g].adj;
  const int* pidx = gpidx(g);
  const float* edoth = G_EDOTH + ((size_t)g*NH + h)*E;
  const float* adn = f + OADN + h*N;
  for (int i=0;i<4;i++){
    float asn = f[OASN + h*N + n0+i];
    for (int j = tid; j < N; j += 128){
      float a = adj[(n0+i)*N + j];
      float zz;
      if (a > 0.f){
        int p = pidx[(n0+i)*N + j];
        float ee = (p >= 0) ? edoth[p] : 0.f;
        zz = lreluf(asn + adn[j] + ee);
      } else zz = -1e9f;
      z[i][j] = zz;
    }
  }
  __syncthreads();
  for (int i=0;i<4;i++){
    float m = -3e38f;
    for (int j = tid; j < N; j += 128) m = fmaxf(m, z[i][j]);
    red[tid] = m; __syncthreads();
    for (int s=64;s>0;s>>=1){ if (tid<s) red[tid]=fmaxf(red[tid],red[tid+s]); __syncthreads(); }
    m = red[0]; __syncthreads();
    float ssum = 0.f;
    for (int j = tid; j < N; j += 128){ float e = expf(z[i][j]-m); z[i][j]=e; ssum += e; }
    red[tid] = ssum; __syncthreads();
    for (int s=64;s>0;s>>=1){ if (tid<s) red[tid]+=red[tid+s]; __syncthreads(); }
    if (tid==0) sinv[i] = 1.f/red[0];
    __syncthreads();
  }
  const float* wh = f + OWH + (size_t)h*N*OUTD;
  float a0=0.f,a1=0.f,a2=0.f,a3=0.f;
  for (int j=0;j<N;j++){
    float w = wh[(size_t)j*OUTD + tid];
    a0 += z[0][j]*w; a1 += z[1][j]*w; a2 += z[2][j]*w; a3 += z[3][j]*w;
  }
  float v0 = eluf(a0*sinv[0]);
  float v1 = eluf(a1*sinv[1]);
  float v2 = eluf(a2*sinv[2]);
  float v3 = eluf(a3*sinv[3]);
  f[OH1 + (size_t)(n0+0)*CAT + h*OUTD + tid] = v0;
  f[OH1 + (size_t)(n0+1)*CAT + h*OUTD + tid] = v1;
  f[OH1 + (size_t)(n0+2)*CAT + h*OUTD + tid] = v2;
  f[OH1 + (size_t)(n0+3)*CAT + h*OUTD + tid] = v3;
  // fused xw1: per-head partial dots -> atomic accumulate
  float w1 = P.ep1_w[h*OUTD + tid];
  float w2 = P.ep1_w[CAT + h*OUTD + tid];
  float w3 = P.g2_w[h*OUTD + tid];
  float pp[12];
  pp[0]=v0*w1; pp[1]=v0*w2; pp[2]=v0*w3;
  pp[3]=v1*w1; pp[4]=v1*w2; pp[5]=v1*w3;
  pp[6]=v2*w1; pp[7]=v2*w2; pp[8]=v2*w3;
  pp[9]=v3*w1; pp[10]=v3*w2; pp[11]=v3*w3;
  #pragma unroll
  for (int k=0;k<12;k++){
    #pragma unroll
    for (int off=32;off>0;off>>=1) pp[k] += __shfl_down(pp[k],off);
  }
  int wv = tid>>6, ln = tid&63;
  if (ln==0){
    #pragma unroll
    for (int k=0;k<12;k++) lxr[wv][k]=pp[k];
  }
  __syncthreads();
  if (tid<12){
    float s = lxr[0][tid]+lxr[1][tid];
    int node = n0 + tid/3, kind = tid%3;
    int base = kind==0 ? OXW1 : (kind==1 ? OXW2 : ORAW2);
    atomicAdd(&f[base + node], s);
  }
}

// ---- merged: Wh2raw (blocks 0..99) + s1 (blocks 100..113); 512 thr ----
DI void wh2_body(Params& P, int nq, int g, char* smem){
  float* hrow = (float*)smem;                  // [4][2048]
  float* part = (float*)(smem + 32768);        // [kq][node][o] = [4][4][128]
  float* lred = (float*)(smem + 32768 + 8192); // [2][8]
  int tid = threadIdx.x;
  float* f = gf(g);
  int n0 = nq*4;
  for (int idx=tid; idx<4*CAT; idx+=512)
    hrow[idx] = f[OH1 + (size_t)(n0 + (idx>>11))*CAT + (idx&2047)];
  __syncthreads();
  int o = tid&127, kq = tid>>7;
  float acc0=0.f, acc1=0.f, acc2=0.f, acc3=0.f;
  const float* W = P.W_out + (size_t)(kq*512)*OUTD + o;
  const float* hA = hrow + kq*512;
  const float* hB = hA + CAT;
  const float* hC = hB + CAT;
  const float* hD = hC + CAT;
  for (int j=0;j<512;j++){
    float w = W[(size_t)j*OUTD];
    acc0 += hA[j]*w; acc1 += hB[j]*w; acc2 += hC[j]*w; acc3 += hD[j]*w;
  }
  part[(kq*4+0)*128+o]=acc0;
  part[(kq*4+1)*128+o]=acc1;
  part[(kq*4+2)*128+o]=acc2;
  part[(kq*4+3)*128+o]=acc3;
  __syncthreads();
  float a[4];
  #pragma unroll
  for (int i=0;i<4;i++)
    a[i] = part[(0*4+i)*128+o]+part[(1*4+i)*128+o]+part[(2*4+i)*128+o]+part[(3*4+i)*128+o];
  if (kq==0){
    #pragma unroll
    for (int i=0;i<4;i++) f[OWH2 + (size_t)(n0+i)*OUTD + o] = a[i];   // RAW (no ns)
  }
  float pr[8];
  #pragma unroll
  for (int i=0;i<4;i++){ pr[i*2] = a[i]*P.ao_src[o]; pr[i*2+1] = a[i]*P.ao_dst[o]; }
  #pragma unroll
  for (int k=0;k<8;k++){
    #pragma unroll
    for (int off=32;off>0;off>>=1) pr[k] += __shfl_down(pr[k],off);
  }
  int wv = tid>>6, ln = tid&63;
  if (wv<2 && ln==0){
    #pragma unroll
    for (int k=0;k<8;k++) lred[wv*8+k]=pr[k];
  }
  __syncthreads();
  if (tid<8){
    float s = lred[tid]+lred[8+tid];
    int node = n0 + (tid>>1);
    if (tid&1) f[OAD2+node]=s; else f[OAS2+node]=s;   // RAW dots
  }
}

DI void s1_body(Params& P, int idx){
  int g = idx/7;
  int e = (idx%7)*512 + threadIdx.x;
  if (e >= E) return;
  float* f = gf(g);
  const int* ei = P.g[g].eidx;
  int s = ei[e], d = ei[E+e];
  float v = sigmf(f[OXW1+s] + f[OXW2+d] + f[OEW1+e] + P.ep1_b[0]);
  f[OS1+e] = v;
  atomicAdd(&f[OSS1+s], v);
  atomicAdd(&f[ODEG1+s], 1.f);
}

__global__ __launch_bounds__(512) void k_s1wh2(Params P){
  __shared__ __attribute__((aligned(16))) char smem[32768 + 8192 + 64];
  int b = blockIdx.x;
  if (b < 100) wh2_body(P, b>>1, b&1, smem);
  else s1_body(P, b-100);
}

// ---- merged: att2-quad (blocks 0..99, ns folded) + pool2 (blocks 100..107) ----
DI void gpool_body(Params& P, int xoff, int D, int odeg, int rawoff,
                   const float* bb, int outoff, int cb, int g,
                   float* att, float* sb){
  int tid = threadIdx.x;
  float* f = gf(g);
  if (tid < N){
    float sc = f[odeg+256+tid]/(f[odeg+tid]+1e-6f);
    att[tid] = sigmf(f[rawoff+tid]*sc + bb[0]);
  }
  __syncthreads();
  float m = (tid < N) ? att[tid] : -3e38f;
  sb[tid] = m; __syncthreads();
  for (int s=256;s>0;s>>=1){ if (tid<s) sb[tid]=fmaxf(sb[tid],sb[tid+s]); __syncthreads(); }
  m = sb[0]; __syncthreads();
  float e = (tid < N) ? expf(att[tid]-m) : 0.f;
  sb[tid] = e; __syncthreads();
  for (int s=256;s>0;s>>=1){ if (tid<s) sb[tid]+=sb[tid+s]; __syncthreads(); }
  float inv = 1.f/sb[0]; __syncthreads();
  if (tid < N){
    float sc = f[odeg+256+tid]/(f[odeg+tid]+1e-6f);
    att[tid] = e*inv*sc;
  }
  __syncthreads();
  int c = cb*512 + tid;
  if (c < D){
    const float* x = f + xoff;
    float acc = 0.f;
    for (int n=0;n<N;n++) acc += att[n]*x[(size_t)n*D + c];
    gxseq()[g*SEQD + outoff + c] = acc;
  }
}

DI void att2_body(Params& P, int nb, int g, char* smem){
  int tid = threadIdx.x;
  int grp = tid>>7, o = tid&127;
  int n0 = nb*4, n = n0 + grp;
  float (*z)[N] = (float(*)[N])smem;                       // [4][200]
  float* nsv = (float*)(smem + 4*N*4);                     // [200]
  float* red = nsv + 256;                                  // [4][128]
  float* inv = red + 512;                                  // [4]
  float* lxr = inv + 4;                                    // [8][3]
  float* f = gf(g);
  const float* adj = P.g[g].adj;
  const int* pidx = gpidx(g);
  for (int j = tid; j < N; j += 512)
    nsv[j] = f[OSS1+j]/(f[ODEG1+j]+1e-6f);
  __syncthreads();
  float asn = f[OAS2+n]*nsv[n];
  for (int j = o; j < N; j += 128){
    float a = adj[n*N + j];
    float zz;
    if (a > 0.f){
      int p = pidx[n*N + j];
      float ee = (p >= 0) ? f[OEWV+p]*f[OS1+p] : 0.f;
      zz = lreluf(asn + f[OAD2+j]*nsv[j] + ee);
    } else zz = -1e9f;
    z[grp][j] = zz;
  }
  __syncthreads();
  float m = -3e38f;
  for (int j = o; j < N; j += 128) m = fmaxf(m, z[grp][j]);
  red[grp*128+o] = m; __syncthreads();
  for (int s=64;s>0;s>>=1){ if (o<s) red[grp*128+o]=fmaxf(red[grp*128+o],red[grp*128+o+s]); __syncthreads(); }
  m = red[grp*128]; __syncthreads();
  float ssum = 0.f;
  for (int j = o; j < N; j += 128){ float e = expf(z[grp][j]-m); z[grp][j]=e; ssum += e; }
  red[grp*128+o] = ssum; __syncthreads();
  for (int s=64;s>0;s>>=1){ if (o<s) red[grp*128+o]+=red[grp*128+o+s]; __syncthreads(); }
  if (o==0) inv[grp] = 1.f/red[grp*128];
  __syncthreads();
  const float* wh = f + OWH2;
  float acc = 0.f;
  for (int j=0;j<N;j++){
    float w = z[grp][j]*nsv[j];
    if (w != 0.f) acc += w * wh[(size_t)j*OUTD + o];
  }
  float v = acc*inv[grp];
  f[OH2B + (size_t)n*OUTD + o] = v;
  float pr[3];
  pr[0] = v*P.ep2_w[o];
  pr[1] = v*P.ep2_w[OUTD+o];
  pr[2] = v*P.g3_w[o];
  #pragma unroll
  for (int k=0;k<3;k++){
    #pragma unroll
    for (int off=32;off>0;off>>=1) pr[k] += __shfl_down(pr[k],off);
  }
  int wv = tid>>6, ln = tid&63;
  if (ln==0){
    lxr[wv*3+0]=pr[0]; lxr[wv*3+1]=pr[1]; lxr[wv*3+2]=pr[2];
  }
  __syncthreads();
  if (tid<12){
    int node = tid/3, kind = tid%3;
    float s = lxr[(node*2)*3+kind] + lxr[(node*2+1)*3+kind];
    int base = kind==0 ? OXS2 : (kind==1 ? OXD2 : ORAW3);
    f[base + n0 + node] = s;
  }
}

__global__ __launch_bounds__(512) void k_att2p(Params P){
  __shared__ __attribute__((aligned(16))) char smem[8192];
  int b = blockIdx.x;
  if (b < 100) att2_body(P, b>>1, b&1, smem);
  else {
    int idx = b-100, g = idx>>2, cb = idx&3;
    float* att = (float*)smem;
    float* sb  = att + 256;
    gpool_body(P, OH1, CAT, ODEG1, ORAW2, P.g2_b, HID, cb, g, att, sb);
  }
}

// ---- finish: sum 4 head-group partials, elu, dot ep2_w; fused s2 ----
constexpr int TE2 = 16;
__global__ void k_ew2fin(Params P){
  int e0 = blockIdx.x*TE2, g = blockIdx.y, tid = threadIdx.x;
  __shared__ float lred[2][TE2];
  float* f = gf(g);
  float w2 = P.ep2_w[2*OUTD + tid];
  int lane = tid & 63, wvi = tid >> 6;
  for (int e=0;e<TE2;e++){
    const float* src = G_E2PART + ((size_t)g*E + e0 + e)*OUTD + tid;
    float a = 0.f;
    #pragma unroll
    for (int h=0;h<4;h++) a += src[(size_t)h*2*E*OUTD];
    float v = eluf(f[OS1+e0+e]*a) * w2;
    for (int off=32;off>0;off>>=1) v += __shfl_down(v,off);
    if (lane==0) lred[wvi][e]=v;
  }
  __syncthreads();
  if (tid < TE2){
    int e = e0 + tid;
    float ew2 = lred[0][tid]+lred[1][tid];
    const int* ei = P.g[g].eidx;
    int s = ei[e], d = ei[E+e];
    float v = sigmf(f[OXS2+s] + f[OXD2+d] + ew2 + P.ep2_b[0]);
    atomicAdd(&f[OSS2+s], v);
    atomicAdd(&f[ODEG2+s], 1.f);
  }
}

// ---- pool3 ----
__global__ __launch_bounds__(512) void k_pool3(Params P){
  __shared__ float att[256];
  __shared__ float sb[512];
  int g = blockIdx.x;
  gpool_body(P, OH2B, OUTD, ODEG2, ORAW3, P.g3_b, HID+CAT, 0, g, att, sb);
}

// ---- LSTM input projection ----
__global__ void k_lstm_xg(Params P, int layer){
  int gid = blockIdx.x*4 + (threadIdx.x>>6);
  int lane = threadIdx.x & 63;
  int t = gid >> 10;
  int rem = gid & 1023;
  int d = rem >> 9;
  int gate = rem & 511;
  const float* Wih = layer ? P.Wih1 : P.Wih0;
  const float* bb  = layer ? P.b1   : P.b0;
  const float* xin = layer ? gy0()  : gxseq();
  int Din = layer ? 256 : SEQD;
  const float* x = xin + t*Din;
  const float* Wr = Wih + ((size_t)d*512 + gate)*Din;
  float acc = 0.f;
  for (int k=lane; k<Din; k+=64) acc += x[k]*Wr[k];
  for (int off=32; off>0; off>>=1) acc += __shfl_down(acc, off);
  if (lane==0) gxg()[(t*2 + d)*512 + gate] = acc + bb[d*512 + gate];
}

// ---- LSTM recurrence layer 0: coalesced via transposed Whh ----
__global__ void k_lstm_rec(Params P, int layer){
  int d = blockIdx.x, tid = threadIdx.x;
  float* yout = layer ? gy1() : gy0();
  const float* T = G_WHHT + (size_t)(layer*2 + d)*128*512;
  __shared__ float h[128], c[128], gbuf[512];
  if (tid < 128){ h[tid]=0.f; c[tid]=0.f; }
  __syncthreads();
  for (int s=0;s<2;s++){
    int t = (d==0) ? s : 1-s;
    float acc = gxg()[(t*2 + d)*512 + tid];
    for (int k=0;k<128;k++) acc += h[k]*T[(size_t)k*512 + tid];
    gbuf[tid] = acc;
    __syncthreads();
    if (tid < 128){
      float ii = sigmf(gbuf[tid]);
      float ff = sigmf(gbuf[128+tid]);
      float gg = tanhf(gbuf[256+tid]);
      float oo = sigmf(gbuf[384+tid]);
      float cn = ff*c[tid] + ii*gg;
      c[tid] = cn;
      float hn = oo*tanhf(cn);
      h[tid] = hn;
      yout[t*256 + d*128 + tid] = hn;
    }
    __syncthreads();
  }
}

// ---- LSTM layer-1 recurrence (both directions) + final FC/softmax, 1 block ----
__global__ __launch_bounds__(1024) void k_recfin(Params P){
  int tid = threadIdx.x;
  int d = tid>>9, gt = tid&511;
  __shared__ float h[2][128], c[2][128], gbuf[2][512], yfin[256];
  __shared__ float sb[256], sb2[256];
  if (gt < 128){ h[d][gt]=0.f; c[d][gt]=0.f; }
  __syncthreads();
  const float* T = G_WHHT + (size_t)(2 + d)*128*512;
  for (int s=0;s<2;s++){
    int t = (d==0) ? s : 1-s;
    float acc = gxg()[(t*2 + d)*512 + gt];
    for (int k=0;k<128;k++) acc += h[d][k]*T[(size_t)k*512 + gt];
    gbuf[d][gt] = acc;
    __syncthreads();
    if (gt < 128){
      float ii = sigmf(gbuf[d][gt]);
      float ff = sigmf(gbuf[d][128+gt]);
      float gg = tanhf(gbuf[d][256+gt]);
      float oo = sigmf(gbuf[d][384+gt]);
      float cn = ff*c[d][gt] + ii*gg;
      c[d][gt] = cn;
      float hn = oo*tanhf(cn);
      h[d][gt] = hn;
      if (t==1) yfin[d*128 + gt] = hn;
    }
    __syncthreads();
  }
  if (tid < 256){
    sb[tid]  = yfin[tid]*P.fc_w[tid*2+0];
    sb2[tid] = yfin[tid]*P.fc_w[tid*2+1];
  }
  __syncthreads();
  for (int s=128;s>0;s>>=1){
    if (tid<s){ sb[tid]+=sb[tid+s]; sb2[tid]+=sb2[tid+s]; }
    __syncthreads();
  }
  if (tid==0){
    float l0 = sb[0] + P.fc_b[0];
    float l1 = sb2[0] + P.fc_b[1];
    float m = fmaxf(l0,l1);
    float e0 = expf(l0-m), e1 = expf(l1-m), inv = 1.f/(e0+e1);
    P.out[0] = e0*inv;
    P.out[1] = e1*inv;
  }
}

extern "C" void kernel_launch(void* const* d_in, const int* in_sizes, int n_in,
                              void* d_out, int out_size, void* d_ws, size_t ws_size,
                              hipStream_t stream){
  Params P;
  for (int g=0; g<2; ++g){
    int b = g*5;
    P.g[g].feat  = (const float*)d_in[b+0];
    P.g[g].eidx  = (const int*)d_in[b+1];
    P.g[g].eattr = (const float*)d_in[b+2];
    P.g[g].adj   = (const float*)d_in[b+3];
    P.g[g].n2n   = (const float*)d_in[b+4];
  }
  P.W_h   = (const float*)d_in[10];
  P.W_gat = (const float*)d_in[11];
  P.a_src = (const float*)d_in[12];
  P.a_dst = (const float*)d_in[13];
  P.a_e   = (const float*)d_in[14];
  P.We_gat= (const float*)d_in[15];
  P.W_out = (const float*)d_in[16];
  P.ao_src= (const float*)d_in[17];
  P.ao_dst= (const float*)d_in[18];
  P.ao_e  = (const float*)d_in[19];
  P.We_out= (const float*)d_in[20];
  P.ep1_w = (const float*)d_in[21];
  P.ep1_b = (const float*)d_in[22];
  P.ep2_w = (const float*)d_in[23];
  P.ep2_b = (const float*)d_in[24];
  P.g1_w  = (const float*)d_in[25];
  P.g1_b  = (const float*)d_in[26];
  P.g2_w  = (const float*)d_in[27];
  P.g2_b  = (const float*)d_in[28];
  P.g3_w  = (const float*)d_in[29];
  P.g3_b  = (const float*)d_in[30];
  P.Wih0  = (const float*)d_in[31];
  P.Whh0  = (const float*)d_in[32];
  P.b0    = (const float*)d_in[33];
  P.Wih1  = (const float*)d_in[34];
  P.Whh1  = (const float*)d_in[35];
  P.b1    = (const float*)d_in[36];
  P.fc_w  = (const float*)d_in[37];
  P.fc_b  = (const float*)d_in[38];
  P.out   = (float*)d_out;

  // ---- graph stages (11 launches) ----
  k_init <<<dim3(IB_TOT), 256, 0, stream>>>(P);
  k_mega <<<dim3(MB_E2P+MB_ED+MB_WH+MB_PR), 256, 0, stream>>>(P);
  k_att1 <<<dim3(N/4,NH,2),128, 0, stream>>>(P);       // +xw1/g2raw fused
  k_s1wh2<<<dim3(114),    512, 0, stream>>>(P);        // Wh2raw || s1
  k_att2p<<<dim3(108),    512, 0, stream>>>(P);        // att2(ns-folded) || pool2
  k_ew2fin<<<dim3(E/TE2,2),128, 0, stream>>>(P);       // +s2
  k_pool3<<<dim3(2),      512, 0, stream>>>(P);
  k_lstm_xg <<<dim3(512), 256, 0, stream>>>(P, 0);
  k_lstm_rec<<<dim3(2),   512, 0, stream>>>(P, 0);
  k_lstm_xg <<<dim3(512), 256, 0, stream>>>(P, 1);
  k_recfin<<<dim3(1),    1024, 0, stream>>>(P);        // rec1 + final
}